// Round 5
// baseline (1867.110 us; speedup 1.0000x reference)
//
#include <hip/hip_runtime.h>
#include <math.h>

typedef __bf16 bf16x8 __attribute__((ext_vector_type(8)));
typedef float f32x4 __attribute__((ext_vector_type(4)));
typedef unsigned short ushort_t;
typedef unsigned int uint_t;

__device__ __forceinline__ ushort_t f2bf(float f) {
    uint_t u = __float_as_uint(f);
    u += 0x7fff + ((u >> 16) & 1);          // RNE
    return (ushort_t)(u >> 16);
}
__device__ __forceinline__ float bf2f(ushort_t h) {
    return __uint_as_float(((uint_t)h) << 16);
}

// async global->LDS, 16B per lane. LDS dest is wave-uniform base + lane*16.
__device__ __forceinline__ void ll16(const ushort_t* g, ushort_t* l) {
    __builtin_amdgcn_global_load_lds(
        (const __attribute__((address_space(1))) unsigned int*)g,
        (__attribute__((address_space(3))) unsigned int*)l, 16, 0, 0);
}

// ---------------- elementwise split: fp32 -> (hi, lo) bf16 ----------------
__global__ __launch_bounds__(256) void split_kernel(
    const float* __restrict__ in, ushort_t* __restrict__ hi,
    ushort_t* __restrict__ lo, long n4)
{
    long i = (long)blockIdx.x * 256 + threadIdx.x;
    if (i >= n4) return;
    float4 v = ((const float4*)in)[i];
    ushort4 h, l;
    h.x = f2bf(v.x); l.x = f2bf(v.x - bf2f(h.x));
    h.y = f2bf(v.y); l.y = f2bf(v.y - bf2f(h.y));
    h.z = f2bf(v.z); l.z = f2bf(v.z - bf2f(h.z));
    h.w = f2bf(v.w); l.w = f2bf(v.w - bf2f(h.w));
    ((ushort4*)hi)[i] = h;
    ((ushort4*)lo)[i] = l;
}

// ------- transpose + split: W [K,N] fp32 row-major -> Wt [Npad,K] bf16 -------
__global__ __launch_bounds__(256) void tsplit_kernel(
    const float* __restrict__ W, ushort_t* __restrict__ hi,
    ushort_t* __restrict__ lo, int K, int N, int write_lo)
{
    __shared__ float t[32][33];
    const int tx = threadIdx.x & 31;
    const int ty = threadIdx.x >> 5;
    const int nb = blockIdx.x * 32;
    const int kb = blockIdx.y * 32;
    #pragma unroll
    for (int i = 0; i < 4; ++i) {
        int k = kb + ty + i * 8;
        int n = nb + tx;
        t[ty + i * 8][tx] = (n < N) ? W[(size_t)k * N + n] : 0.f;
    }
    __syncthreads();
    #pragma unroll
    for (int i = 0; i < 4; ++i) {
        int n = nb + ty + i * 8;
        int k = kb + tx;
        float f = t[tx][ty + i * 8];
        size_t idx = (size_t)n * K + k;
        ushort_t h = f2bf(f);
        hi[idx] = h;
        if (write_lo) lo[idx] = f2bf(f - bf2f(h));
    }
}

// ---------------- MFMA GEMM: C = A @ Bt^T (+bias, +relu) ----------------
// 128x128 block tile, 2x2 waves of 64x64, 16x16x32 bf16 MFMA, m97 rhythm:
// 16 KB staged + 4 ll16/thread + 8 ds_read_b128 + 16 MFMA per wave per iter.
// NPASS==3 folds the split-precision sum Ahi*Bhi + Alo*Bhi + Ahi*Blo into
// K' = 3K via wave-uniform segment pointer selection (no materialization).
template <int NPASS>
__global__ __launch_bounds__(256) void gemm_mfma(
    const ushort_t* __restrict__ Ahi, const ushort_t* __restrict__ Alo,
    const ushort_t* __restrict__ Bhi, const ushort_t* __restrict__ Blo,
    const float* __restrict__ bias,
    float* __restrict__ Cf, ushort_t* __restrict__ Chi, ushort_t* __restrict__ Clo,
    int K, int Ntrue, int ldc, int relu_flag,
    const int* __restrict__ rowidx, const int* __restrict__ cntp, int Mfull)
{
    __shared__ __align__(16) ushort_t As[4096];   // 128 rows x 32 k
    __shared__ __align__(16) ushort_t Bs[4096];

    const int tid = threadIdx.x;
    const int m0 = blockIdx.y * 128, n0 = blockIdx.x * 128;
    int Meff = Mfull;
    if (cntp) Meff = *cntp;
    if (m0 >= ((Meff + 127) & ~127)) return;   // block-uniform early exit

    const int lane = tid & 63, wave = tid >> 6;
    const int wm = wave >> 1, wn = wave & 1;   // 2x2 waves, 64x64 each
    const int q = lane >> 4, r16 = lane & 15;

    // staging chunk = tid: row = tid&127, kb = tid>>7 (0..1); 2nd chunk kb+2
    const int srow = tid & 127;
    const int skb = tid >> 7;
    int arow = m0 + srow;
    if (rowidx) arow = rowidx[(arow < Meff) ? arow : (Meff - 1)];
    const size_t ga = (size_t)arow * K + skb * 8;
    const size_t gb = (size_t)(n0 + srow) * K + skb * 8;

    // wave-uniform LDS bases (HW adds lane*16B); +2048 ushorts = chunks kb+2
    ushort_t* const a0 = &As[wave * 512];
    ushort_t* const b0 = &Bs[wave * 512];

    f32x4 acc[4][4];
    #pragma unroll
    for (int i = 0; i < 4; ++i)
        #pragma unroll
        for (int j = 0; j < 4; ++j) acc[i][j] = (f32x4)(0.f);

    const int fa = (q * 128 + wm * 64 + r16) * 8;
    const int fb = (q * 128 + wn * 64 + r16) * 8;

    for (int pass = 0; pass < NPASS; ++pass) {
        // pass 0: hi*hi, pass 1: lo*hi, pass 2: hi*lo (wave-uniform selects)
        const ushort_t* __restrict__ Ap = (pass == 1) ? Alo : Ahi;
        const ushort_t* __restrict__ Bp = (pass == 2) ? Blo : Bhi;
        for (int k0 = 0; k0 < K; k0 += 32) {
            __syncthreads();   // prior iteration's frag reads complete
            ll16(Ap + ga + k0,      a0);
            ll16(Ap + ga + k0 + 16, a0 + 2048);
            ll16(Bp + gb + k0,      b0);
            ll16(Bp + gb + k0 + 16, b0 + 2048);
            __syncthreads();   // vmcnt(0) drain + barrier: staging visible

            bf16x8 ah[4];
            #pragma unroll
            for (int mi = 0; mi < 4; ++mi)
                ah[mi] = *(const bf16x8*)(&As[fa + mi * 128]);
            #pragma unroll
            for (int nj = 0; nj < 4; ++nj) {
                bf16x8 bh = *(const bf16x8*)(&Bs[fb + nj * 128]);
                #pragma unroll
                for (int mi = 0; mi < 4; ++mi)
                    acc[mi][nj] = __builtin_amdgcn_mfma_f32_16x16x32_bf16(ah[mi], bh, acc[mi][nj], 0, 0, 0);
            }
        }
    }

    // epilogue: D layout per 16x16 tile: row = q*4 + r, col = r16
    #pragma unroll
    for (int mi = 0; mi < 4; ++mi) {
        #pragma unroll
        for (int nj = 0; nj < 4; ++nj) {
            const int col = n0 + wn * 64 + nj * 16 + r16;
            const int rowb = m0 + wm * 64 + mi * 16 + q * 4;
            const float bv = (col < Ntrue) ? bias[col] : 0.f;
            #pragma unroll
            for (int r = 0; r < 4; ++r) {
                float v = acc[mi][nj][r] + bv;
                if (relu_flag) v = fmaxf(v, 0.f);
                const size_t idx = (size_t)(rowb + r) * ldc + col;
                if (Cf) {
                    if (col < Ntrue) Cf[idx] = v;
                } else {
                    ushort_t h = f2bf(v);
                    Chi[idx] = h;
                    if (NPASS == 3) Clo[idx] = f2bf(v - bf2f(h));
                }
            }
        }
    }
}

// ---- exit mask: max softmax prob > 0.01  <=>  sum(exp(l - max)) < 100 ----
__global__ __launch_bounds__(256) void conf_kernel(
    const float* __restrict__ P, int N, int* __restrict__ cm,
    const int* __restrict__ cntp)
{
    const int b = blockIdx.x;
    if (cntp && b >= *cntp) return;
    const float* row = P + (size_t)b * N;
    float m = -3.0e38f;
    for (int c = threadIdx.x; c < N; c += 256) m = fmaxf(m, row[c]);
    #pragma unroll
    for (int off = 32; off > 0; off >>= 1) m = fmaxf(m, __shfl_down(m, off));
    __shared__ float red_max[4];
    __shared__ float red_sum[4];
    const int wave = threadIdx.x >> 6;
    const int lane = threadIdx.x & 63;
    if (lane == 0) red_max[wave] = m;
    __syncthreads();
    m = fmaxf(fmaxf(red_max[0], red_max[1]), fmaxf(red_max[2], red_max[3]));
    float s = 0.f;
    for (int c = threadIdx.x; c < N; c += 256) s += expf(row[c] - m);
    #pragma unroll
    for (int off = 32; off > 0; off >>= 1) s += __shfl_down(s, off);
    if (lane == 0) red_sum[wave] = s;
    __syncthreads();
    if (threadIdx.x == 0) {
        float tot = red_sum[0] + red_sum[1] + red_sum[2] + red_sum[3];
        cm[b] = (tot < 100.0f) ? 1 : 0;
    }
}

__global__ void init_kernel(int* cnt1, int* cnt2) {
    if (threadIdx.x == 0) { *cnt1 = 0; *cnt2 = 0; }
}

// compact: positions i < nlim with mask[i]==0 -> idx[atomic slot]
__global__ __launch_bounds__(256) void build_kernel(
    const int* __restrict__ mask, int n, const int* __restrict__ nlimp,
    int* __restrict__ cnt, int* __restrict__ idx)
{
    int i = blockIdx.x * 256 + threadIdx.x;
    int nl = nlimp ? *nlimp : n;
    if (i >= nl) return;
    if (!mask[i]) { int p = atomicAdd(cnt, 1); idx[p] = i; }
}

// out[idx1[j]] = p2[j]  where j survived stage1 but exited at stage2
__global__ __launch_bounds__(256) void scatter2_kernel(
    float* __restrict__ out, const float* __restrict__ p2,
    const int* __restrict__ idx1, const int* __restrict__ c2m,
    const int* __restrict__ cntp, int N)
{
    const int j = blockIdx.y;
    if (j >= *cntp || !c2m[j]) return;
    const int c = blockIdx.x * 256 + threadIdx.x;
    if (c >= N) return;
    out[(size_t)idx1[j] * N + c] = p2[(size_t)j * N + c];
}

// out[idx1[idx2[jj]]] = p3[jj]  for rows that reached stage 3
__global__ __launch_bounds__(256) void scatter3_kernel(
    float* __restrict__ out, const float* __restrict__ p3,
    const int* __restrict__ idx1, const int* __restrict__ idx2,
    const int* __restrict__ cntp, int N)
{
    const int jj = blockIdx.y;
    if (jj >= *cntp) return;
    const int c = blockIdx.x * 256 + threadIdx.x;
    if (c >= N) return;
    out[(size_t)idx1[idx2[jj]] * N + c] = p3[(size_t)jj * N + c];
}

extern "C" void kernel_launch(void* const* d_in, const int* in_sizes, int n_in,
                              void* d_out, int out_size, void* d_ws, size_t ws_size,
                              hipStream_t stream)
{
    const float* x   = (const float*)d_in[0];
    const float* W1  = (const float*)d_in[1];
    const float* b1  = (const float*)d_in[2];
    const float* W2  = (const float*)d_in[3];
    const float* b2  = (const float*)d_in[4];
    const float* W3  = (const float*)d_in[5];
    const float* b3  = (const float*)d_in[6];
    const float* H1w = (const float*)d_in[7];
    const float* H1b = (const float*)d_in[8];
    const float* H2w = (const float*)d_in[9];
    const float* H2b = (const float*)d_in[10];
    const float* Fw  = (const float*)d_in[11];
    const float* Fb  = (const float*)d_in[12];
    float* out = (float*)d_out;

    const int B = 8192, D = 2048, Hh = 2048, Cc = 1000;

    // ---- workspace carve (~192 MB; ushort units) ----
    ushort_t* xhi  = (ushort_t*)d_ws;             // B*D  (reused: h2hi compact)
    ushort_t* xlo  = xhi + (size_t)B * D;         // B*D  (reused: h2lo compact)
    ushort_t* h1hi = xlo + (size_t)B * D;         // B*H  (reused: h3hi compact)
    ushort_t* h1lo = h1hi + (size_t)B * Hh;       // B*H  (reused: p3 compact fp32)
    ushort_t* W0hi = h1lo + (size_t)B * Hh;       // 2048x2048 (W1t/W2t/W3t)
    ushort_t* W0lo = W0hi + (size_t)Hh * Hh;
    ushort_t* W1thi = W0lo + (size_t)Hh * Hh;     // 1024x2048 (heads)
    ushort_t* W1tlo = W1thi + (size_t)1024 * Hh;
    float* p2 = (float*)(W1tlo + (size_t)1024 * Hh);  // B*Cc fp32 (compact)
    int* c1   = (int*)(p2 + (size_t)B * Cc);      // B  dense stage-1 mask
    int* c2m  = c1 + B;                           // B  stage-2 mask (compact space)
    int* idx1 = c2m + B;                          // B
    int* idx2 = idx1 + B;                         // B
    int* cnt1 = idx2 + B;
    int* cnt2 = cnt1 + 1;

    ushort_t* h2hi = xhi;  ushort_t* h2lo = xlo;
    ushort_t* h3hi = h1hi;
    float* p3 = (float*)h1lo;

    dim3 blk(256);
    const dim3 gBB(16, 64);   // backbone GEMM (2048/128, 8192/128)
    const dim3 gHD(8, 64);    // head GEMM (1024/128, 8192/128)
    const dim3 gT2(64, 64);   // tsplit 2048x2048
    const dim3 gTH(32, 64);   // tsplit head

    init_kernel<<<1, 64, 0, stream>>>(cnt1, cnt2);

    // Stage 1 (dense)
    split_kernel<<<(B * D / 4 + 255) / 256, blk, 0, stream>>>(x, xhi, xlo, (long)B * D / 4);
    tsplit_kernel<<<gT2, blk, 0, stream>>>(W1, W0hi, W0lo, D, Hh, 1);
    gemm_mfma<3><<<gBB, blk, 0, stream>>>(xhi, xlo, W0hi, W0lo, b1,
                                          nullptr, h1hi, h1lo, D, Hh, Hh, 1,
                                          nullptr, nullptr, B);
    tsplit_kernel<<<gTH, blk, 0, stream>>>(H1w, W1thi, W1tlo, Hh, Cc, 1);
    gemm_mfma<3><<<gHD, blk, 0, stream>>>(h1hi, h1lo, W1thi, W1tlo, H1b,
                                          out, nullptr, nullptr, Hh, Cc, Cc, 0,
                                          nullptr, nullptr, B);
    conf_kernel<<<dim3(B), blk, 0, stream>>>(out, Cc, c1, nullptr);
    build_kernel<<<dim3(B / 256), blk, 0, stream>>>(c1, B, nullptr, cnt1, idx1);

    // Stage 2 (compacted to !c1 rows)
    tsplit_kernel<<<gT2, blk, 0, stream>>>(W2, W0hi, W0lo, Hh, Hh, 1);
    gemm_mfma<3><<<gBB, blk, 0, stream>>>(h1hi, h1lo, W0hi, W0lo, b2,
                                          nullptr, h2hi, h2lo, Hh, Hh, Hh, 1,
                                          idx1, cnt1, B);
    tsplit_kernel<<<gTH, blk, 0, stream>>>(H2w, W1thi, W1tlo, Hh, Cc, 1);
    gemm_mfma<3><<<gHD, blk, 0, stream>>>(h2hi, h2lo, W1thi, W1tlo, H2b,
                                          p2, nullptr, nullptr, Hh, Cc, Cc, 0,
                                          nullptr, cnt1, B);
    conf_kernel<<<dim3(B), blk, 0, stream>>>(p2, Cc, c2m, cnt1);
    build_kernel<<<dim3(B / 256), blk, 0, stream>>>(c2m, B, cnt1, cnt2, idx2);

    // Stage 3 (compacted to !c1 && !c2 rows; plain bf16 single pass)
    tsplit_kernel<<<gT2, blk, 0, stream>>>(W3, W0hi, nullptr, Hh, Hh, 0);
    gemm_mfma<1><<<gBB, blk, 0, stream>>>(h2hi, nullptr, W0hi, nullptr, b3,
                                          nullptr, h3hi, nullptr, Hh, Hh, Hh, 1,
                                          idx2, cnt2, B);
    tsplit_kernel<<<gTH, blk, 0, stream>>>(Fw, W1thi, nullptr, Hh, Cc, 0);
    gemm_mfma<1><<<gHD, blk, 0, stream>>>(h3hi, nullptr, W1thi, nullptr, Fb,
                                          p3, nullptr, nullptr, Hh, Cc, Cc, 0,
                                          nullptr, cnt2, B);

    // Merge: out holds p1; overwrite stage-2 exits then stage-3 rows
    scatter2_kernel<<<dim3((Cc + 255) / 256, B), blk, 0, stream>>>(out, p2, idx1, c2m, cnt1, Cc);
    scatter3_kernel<<<dim3((Cc + 255) / 256, B), blk, 0, stream>>>(out, p3, idx1, idx2, cnt2, Cc);
}

// Round 6
// 1162.328 us; speedup vs baseline: 1.6064x; 1.6064x over previous
//
#include <hip/hip_runtime.h>
#include <math.h>

typedef __bf16 bf16x8 __attribute__((ext_vector_type(8)));
typedef float f32x4 __attribute__((ext_vector_type(4)));
typedef unsigned short ushort_t;
typedef unsigned int uint_t;

__device__ __forceinline__ ushort_t f2bf(float f) {
    uint_t u = __float_as_uint(f);
    u += 0x7fff + ((u >> 16) & 1);          // RNE
    return (ushort_t)(u >> 16);
}
__device__ __forceinline__ float bf2f(ushort_t h) {
    return __uint_as_float(((uint_t)h) << 16);
}

// Packed tile-major layout == the GEMM's LDS image, so staging is contiguous.
// element (row,k) -> ((band*(K/32)+kc)*512 + kq*128 + r)*8 + ki
//   band=row>>7, r=row&127, kc=k>>5, kq=(k>>3)&3, ki=k&7
__device__ __forceinline__ size_t poff(int row, int k, int Kdim) {
    return ((((size_t)(row >> 7) * (Kdim >> 5) + (k >> 5)) * 512)
            + ((k >> 3) & 3) * 128 + (row & 127)) * 8 + (k & 7);
}

// async global->LDS, 16B per lane. LDS dest is wave-uniform base + lane*16.
__device__ __forceinline__ void ll16(const ushort_t* g, ushort_t* l) {
    __builtin_amdgcn_global_load_lds(
        (const __attribute__((address_space(1))) unsigned int*)g,
        (__attribute__((address_space(3))) unsigned int*)l, 16, 0, 0);
}

// ---- split x (row-major fp32) -> packed hi/lo bf16. one thread = 8 k ----
__global__ __launch_bounds__(256) void split_kernel(
    const float* __restrict__ in, ushort_t* __restrict__ hi,
    ushort_t* __restrict__ lo, int Kdim)
{
    const int i = blockIdx.x * 256 + threadIdx.x;
    const int row = i >> 8;            // Kdim==2048: 256 octets per row
    const int k = (i & 255) * 8;
    const float4 v0 = *(const float4*)(in + (size_t)row * Kdim + k);
    const float4 v1 = *(const float4*)(in + (size_t)row * Kdim + k + 4);
    const float f[8] = {v0.x, v0.y, v0.z, v0.w, v1.x, v1.y, v1.z, v1.w};
    ushort_t h[8], l[8];
    #pragma unroll
    for (int j = 0; j < 8; ++j) {
        h[j] = f2bf(f[j]);
        l[j] = f2bf(f[j] - bf2f(h[j]));
    }
    const size_t o = poff(row, k, Kdim);
    *(uint4*)(hi + o) = *(const uint4*)h;
    *(uint4*)(lo + o) = *(const uint4*)l;
}

// ---- transpose+split W [K,N] fp32 -> packed Wt over padded N rows ----
__global__ __launch_bounds__(256) void tsplit_kernel(
    const float* __restrict__ W, ushort_t* __restrict__ hi,
    ushort_t* __restrict__ lo, int K, int N, int write_lo)
{
    __shared__ float t[32][33];
    const int tx = threadIdx.x & 31;
    const int ty = threadIdx.x >> 5;
    const int nb = blockIdx.x * 32;
    const int kb = blockIdx.y * 32;
    #pragma unroll
    for (int i = 0; i < 4; ++i) {
        int k = kb + ty + i * 8;
        int n = nb + tx;
        t[ty + i * 8][tx] = (n < N) ? W[(size_t)k * N + n] : 0.f;
    }
    __syncthreads();
    #pragma unroll
    for (int i = 0; i < 4; ++i) {
        int n = nb + ty + i * 8;           // output row (padded space)
        int k = kb + tx;
        float f = t[tx][ty + i * 8];
        size_t idx = poff(n, k, K);
        ushort_t h = f2bf(f);
        hi[idx] = h;
        if (write_lo) lo[idx] = f2bf(f - bf2f(h));
    }
}

// ---- gather-pack: dest packed row j <- src packed row idx[j] ----
__global__ __launch_bounds__(256) void gather_pack(
    const ushort_t* __restrict__ srchi, const ushort_t* __restrict__ srclo,
    ushort_t* __restrict__ dsthi, ushort_t* __restrict__ dstlo,
    const int* __restrict__ idx, const int* __restrict__ cntp, int Kdim)
{
    const int j = blockIdx.x;
    if (j >= *cntp) return;
    const int srow = idx[j];
    const int k = threadIdx.x * 8;     // Kdim==2048, 256 threads
    const size_t so = poff(srow, k, Kdim);
    const size_t dofs = poff(j, k, Kdim);
    *(uint4*)(dsthi + dofs) = *(const uint4*)(srchi + so);
    if (srclo) *(uint4*)(dstlo + dofs) = *(const uint4*)(srclo + so);
}

// ---------------- MFMA GEMM: C = A @ Bt^T (+bias, +relu) ----------------
// 128x128 block tile, 2x2 waves of 64x64, 16x16x32 bf16 MFMA (R3 structure).
// A, Bt in PACKED layout -> staging is contiguous 16 KB slabs per operand.
// NPASS==3: split precision acc += Ahi*Bhi + Alo*Bhi + Ahi*Blo (interleaved).
template <int NPASS>
__global__ __launch_bounds__(256) void gemm_mfma(
    const ushort_t* __restrict__ Ahi, const ushort_t* __restrict__ Alo,
    const ushort_t* __restrict__ Bhi, const ushort_t* __restrict__ Blo,
    const float* __restrict__ bias,
    float* __restrict__ Cf, ushort_t* __restrict__ Chi, ushort_t* __restrict__ Clo,
    int K, int Ntrue, int ldc, int relu_flag,
    const int* __restrict__ cntp, int Mfull)
{
    __shared__ __align__(16) ushort_t As[NPASS == 3 ? 2 : 1][4096];
    __shared__ __align__(16) ushort_t Bs[NPASS == 3 ? 2 : 1][4096];

    const int tid = threadIdx.x;
    const int m0 = blockIdx.y * 128, n0 = blockIdx.x * 128;
    int Meff = Mfull;
    if (cntp) Meff = *cntp;
    if (m0 >= ((Meff + 127) & ~127)) return;   // block-uniform early exit

    const int lane = tid & 63, wave = tid >> 6;
    const int wm = wave >> 1, wn = wave & 1;   // 2x2 waves, 64x64 each
    const int q = lane >> 4, r16 = lane & 15;

    // packed slab streams: slab (band, kc) is 4096 contiguous elements
    const ushort_t* pAh = Ahi + (size_t)blockIdx.y * (K >> 5) * 4096 + tid * 8;
    const ushort_t* pBh = Bhi + (size_t)blockIdx.x * (K >> 5) * 4096 + tid * 8;
    const ushort_t* pAl = nullptr; const ushort_t* pBl = nullptr;
    if (NPASS == 3) {
        pAl = Alo + (size_t)blockIdx.y * (K >> 5) * 4096 + tid * 8;
        pBl = Blo + (size_t)blockIdx.x * (K >> 5) * 4096 + tid * 8;
    }

    // wave-uniform LDS bases (HW adds lane*16B); +2048 elements = chunks +256
    ushort_t* const a0 = &As[0][wave * 512];
    ushort_t* const b0 = &Bs[0][wave * 512];
    ushort_t* const a1 = &As[NPASS == 3 ? 1 : 0][wave * 512];
    ushort_t* const b1 = &Bs[NPASS == 3 ? 1 : 0][wave * 512];

    f32x4 acc[4][4];
    #pragma unroll
    for (int i = 0; i < 4; ++i)
        #pragma unroll
        for (int j = 0; j < 4; ++j) acc[i][j] = (f32x4)(0.f);

    const int fa = (q * 128 + wm * 64 + r16) * 8;
    const int fb = (q * 128 + wn * 64 + r16) * 8;

    const int niter = K >> 5;
    for (int it = 0; it < niter; ++it) {
        __syncthreads();   // prior iteration's frag reads complete
        ll16(pAh,        a0);
        ll16(pAh + 2048, a0 + 2048);
        ll16(pBh,        b0);
        ll16(pBh + 2048, b0 + 2048);
        if (NPASS == 3) {
            ll16(pAl,        a1);
            ll16(pAl + 2048, a1 + 2048);
            ll16(pBl,        b1);
            ll16(pBl + 2048, b1 + 2048);
        }
        pAh += 4096; pBh += 4096;
        if (NPASS == 3) { pAl += 4096; pBl += 4096; }
        __syncthreads();   // vmcnt(0) drain + barrier: staging visible

        bf16x8 ah[4], al[4];
        #pragma unroll
        for (int mi = 0; mi < 4; ++mi) {
            ah[mi] = *(const bf16x8*)(&As[0][fa + mi * 128]);
            if (NPASS == 3) al[mi] = *(const bf16x8*)(&As[1][fa + mi * 128]);
        }
        #pragma unroll
        for (int nj = 0; nj < 4; ++nj) {
            bf16x8 bh = *(const bf16x8*)(&Bs[0][fb + nj * 128]);
            bf16x8 bl;
            if (NPASS == 3) bl = *(const bf16x8*)(&Bs[1][fb + nj * 128]);
            #pragma unroll
            for (int mi = 0; mi < 4; ++mi) {
                acc[mi][nj] = __builtin_amdgcn_mfma_f32_16x16x32_bf16(ah[mi], bh, acc[mi][nj], 0, 0, 0);
                if (NPASS == 3) {
                    acc[mi][nj] = __builtin_amdgcn_mfma_f32_16x16x32_bf16(al[mi], bh, acc[mi][nj], 0, 0, 0);
                    acc[mi][nj] = __builtin_amdgcn_mfma_f32_16x16x32_bf16(ah[mi], bl, acc[mi][nj], 0, 0, 0);
                }
            }
        }
    }

    // epilogue: D layout per 16x16 tile: row = q*4 + r, col = r16
    #pragma unroll
    for (int mi = 0; mi < 4; ++mi) {
        #pragma unroll
        for (int nj = 0; nj < 4; ++nj) {
            const int col = n0 + wn * 64 + nj * 16 + r16;
            const int rowb = m0 + wm * 64 + mi * 16 + q * 4;
            const float bv = (col < Ntrue) ? bias[col] : 0.f;
            #pragma unroll
            for (int r = 0; r < 4; ++r) {
                float v = acc[mi][nj][r] + bv;
                if (relu_flag) v = fmaxf(v, 0.f);
                if (Cf) {
                    if (col < Ntrue) Cf[(size_t)(rowb + r) * ldc + col] = v;
                } else {
                    const size_t idx = poff(rowb + r, col, ldc);  // packed dest
                    ushort_t h = f2bf(v);
                    Chi[idx] = h;
                    if (NPASS == 3) Clo[idx] = f2bf(v - bf2f(h));
                }
            }
        }
    }
}

// ---- exit mask: max softmax prob > 0.01  <=>  sum(exp(l - max)) < 100 ----
__global__ __launch_bounds__(256) void conf_kernel(
    const float* __restrict__ P, int N, int* __restrict__ cm,
    const int* __restrict__ cntp)
{
    const int b = blockIdx.x;
    if (cntp && b >= *cntp) return;
    const float* row = P + (size_t)b * N;
    float m = -3.0e38f;
    for (int c = threadIdx.x; c < N; c += 256) m = fmaxf(m, row[c]);
    #pragma unroll
    for (int off = 32; off > 0; off >>= 1) m = fmaxf(m, __shfl_down(m, off));
    __shared__ float red_max[4];
    __shared__ float red_sum[4];
    const int wave = threadIdx.x >> 6;
    const int lane = threadIdx.x & 63;
    if (lane == 0) red_max[wave] = m;
    __syncthreads();
    m = fmaxf(fmaxf(red_max[0], red_max[1]), fmaxf(red_max[2], red_max[3]));
    float s = 0.f;
    for (int c = threadIdx.x; c < N; c += 256) s += expf(row[c] - m);
    #pragma unroll
    for (int off = 32; off > 0; off >>= 1) s += __shfl_down(s, off);
    if (lane == 0) red_sum[wave] = s;
    __syncthreads();
    if (threadIdx.x == 0) {
        float tot = red_sum[0] + red_sum[1] + red_sum[2] + red_sum[3];
        cm[b] = (tot < 100.0f) ? 1 : 0;
    }
}

__global__ void init_kernel(int* cnt1, int* cnt2) {
    if (threadIdx.x == 0) { *cnt1 = 0; *cnt2 = 0; }
}

// compact: positions i < nlim with mask[i]==0 -> idx[atomic slot]
__global__ __launch_bounds__(256) void build_kernel(
    const int* __restrict__ mask, int n, const int* __restrict__ nlimp,
    int* __restrict__ cnt, int* __restrict__ idx)
{
    int i = blockIdx.x * 256 + threadIdx.x;
    int nl = nlimp ? *nlimp : n;
    if (i >= nl) return;
    if (!mask[i]) { int p = atomicAdd(cnt, 1); idx[p] = i; }
}

// out[idx1[j]] = p2[j]  where j survived stage1 but exited at stage2
__global__ __launch_bounds__(256) void scatter2_kernel(
    float* __restrict__ out, const float* __restrict__ p2,
    const int* __restrict__ idx1, const int* __restrict__ c2m,
    const int* __restrict__ cntp, int N)
{
    const int j = blockIdx.y;
    if (j >= *cntp || !c2m[j]) return;
    const int c = blockIdx.x * 256 + threadIdx.x;
    if (c >= N) return;
    out[(size_t)idx1[j] * N + c] = p2[(size_t)j * N + c];
}

// out[idx1[idx2[jj]]] = p3[jj]  for rows that reached stage 3
__global__ __launch_bounds__(256) void scatter3_kernel(
    float* __restrict__ out, const float* __restrict__ p3,
    const int* __restrict__ idx1, const int* __restrict__ idx2,
    const int* __restrict__ cntp, int N)
{
    const int jj = blockIdx.y;
    if (jj >= *cntp) return;
    const int c = blockIdx.x * 256 + threadIdx.x;
    if (c >= N) return;
    out[(size_t)idx1[idx2[jj]] * N + c] = p3[(size_t)jj * N + c];
}

extern "C" void kernel_launch(void* const* d_in, const int* in_sizes, int n_in,
                              void* d_out, int out_size, void* d_ws, size_t ws_size,
                              hipStream_t stream)
{
    const float* x   = (const float*)d_in[0];
    const float* W1  = (const float*)d_in[1];
    const float* b1  = (const float*)d_in[2];
    const float* W2  = (const float*)d_in[3];
    const float* b2  = (const float*)d_in[4];
    const float* W3  = (const float*)d_in[5];
    const float* b3  = (const float*)d_in[6];
    const float* H1w = (const float*)d_in[7];
    const float* H1b = (const float*)d_in[8];
    const float* H2w = (const float*)d_in[9];
    const float* H2b = (const float*)d_in[10];
    const float* Fw  = (const float*)d_in[11];
    const float* Fb  = (const float*)d_in[12];
    float* out = (float*)d_out;

    const int B = 8192, D = 2048, Hh = 2048, Cc = 1000;

    // ---- workspace carve (~185 MB; ushort units) ----
    ushort_t* xhi  = (ushort_t*)d_ws;             // B*D  packed x-hi  (-> h1c-hi -> h2c-hi)
    ushort_t* xlo  = xhi + (size_t)B * D;         // B*D  packed x-lo  (-> h1c-lo -> p3 fp32)
    ushort_t* h1hi = xlo + (size_t)B * D;         // B*H  packed h1-hi (-> h2-hi -> h3-hi)
    ushort_t* h1lo = h1hi + (size_t)B * Hh;       // B*H  packed h1-lo (-> h2-lo)
    ushort_t* W0hi = h1lo + (size_t)B * Hh;       // 2048x2048 packed (W1t/W2t/W3t)
    ushort_t* W0lo = W0hi + (size_t)Hh * Hh;
    ushort_t* W1thi = W0lo + (size_t)Hh * Hh;     // 1024x2048 packed (heads)
    ushort_t* W1tlo = W1thi + (size_t)1024 * Hh;
    float* p2 = (float*)(W1tlo + (size_t)1024 * Hh);  // B*Cc fp32 (compact)
    int* c1   = (int*)(p2 + (size_t)B * Cc);
    int* c2m  = c1 + B;
    int* idx1 = c2m + B;
    int* idx2 = idx1 + B;
    int* cnt1 = idx2 + B;
    int* cnt2 = cnt1 + 1;

    ushort_t* h1chi = xhi;  ushort_t* h1clo = xlo;   // after x dead
    ushort_t* h2hi = h1hi;  ushort_t* h2lo = h1lo;   // after h1 dead
    ushort_t* h2chi = xhi;                            // after h1c dead
    ushort_t* h3hi = h1hi;                            // after h2 dead
    float* p3 = (float*)xlo;                          // after h1c-lo dead

    dim3 blk(256);
    const dim3 gBB(16, 64);   // backbone GEMM (2048/128, 8192/128)
    const dim3 gHD(8, 64);    // head GEMM (1024/128, 8192/128)
    const dim3 gT2(64, 64);   // tsplit 2048x2048
    const dim3 gTH(32, 64);   // tsplit head (Npad=1024)

    init_kernel<<<1, 64, 0, stream>>>(cnt1, cnt2);

    // Stage 1 (dense)
    split_kernel<<<dim3(B * D / 8 / 256), blk, 0, stream>>>(x, xhi, xlo, D);
    tsplit_kernel<<<gT2, blk, 0, stream>>>(W1, W0hi, W0lo, D, Hh, 1);
    gemm_mfma<3><<<gBB, blk, 0, stream>>>(xhi, xlo, W0hi, W0lo, b1,
                                          nullptr, h1hi, h1lo, D, Hh, Hh, 1,
                                          nullptr, B);
    tsplit_kernel<<<gTH, blk, 0, stream>>>(H1w, W1thi, W1tlo, Hh, Cc, 1);
    gemm_mfma<3><<<gHD, blk, 0, stream>>>(h1hi, h1lo, W1thi, W1tlo, H1b,
                                          out, nullptr, nullptr, Hh, Cc, Cc, 0,
                                          nullptr, B);
    conf_kernel<<<dim3(B), blk, 0, stream>>>(out, Cc, c1, nullptr);
    build_kernel<<<dim3(B / 256), blk, 0, stream>>>(c1, B, nullptr, cnt1, idx1);

    // Stage 2 (compacted to !c1 rows; gather-pack then dense-packed GEMM)
    gather_pack<<<dim3(B), blk, 0, stream>>>(h1hi, h1lo, h1chi, h1clo, idx1, cnt1, Hh);
    tsplit_kernel<<<gT2, blk, 0, stream>>>(W2, W0hi, W0lo, Hh, Hh, 1);
    gemm_mfma<3><<<gBB, blk, 0, stream>>>(h1chi, h1clo, W0hi, W0lo, b2,
                                          nullptr, h2hi, h2lo, Hh, Hh, Hh, 1,
                                          cnt1, B);
    tsplit_kernel<<<gTH, blk, 0, stream>>>(H2w, W1thi, W1tlo, Hh, Cc, 1);
    gemm_mfma<3><<<gHD, blk, 0, stream>>>(h2hi, h2lo, W1thi, W1tlo, H2b,
                                          p2, nullptr, nullptr, Hh, Cc, Cc, 0,
                                          cnt1, B);
    conf_kernel<<<dim3(B), blk, 0, stream>>>(p2, Cc, c2m, cnt1);
    build_kernel<<<dim3(B / 256), blk, 0, stream>>>(c2m, B, cnt1, cnt2, idx2);

    // Stage 3 (compacted to !c1 && !c2; plain bf16 single pass)
    gather_pack<<<dim3(B), blk, 0, stream>>>(h2hi, nullptr, h2chi, nullptr, idx2, cnt2, Hh);
    tsplit_kernel<<<gT2, blk, 0, stream>>>(W3, W0hi, nullptr, Hh, Hh, 0);
    gemm_mfma<1><<<gBB, blk, 0, stream>>>(h2chi, nullptr, W0hi, nullptr, b3,
                                          nullptr, h3hi, nullptr, Hh, Hh, Hh, 1,
                                          cnt2, B);
    tsplit_kernel<<<gTH, blk, 0, stream>>>(Fw, W1thi, nullptr, Hh, Cc, 0);
    gemm_mfma<1><<<gHD, blk, 0, stream>>>(h3hi, nullptr, W1thi, nullptr, Fb,
                                          p3, nullptr, nullptr, Hh, Cc, Cc, 0,
                                          cnt2, B);

    // Merge: out holds p1; overwrite stage-2 exits then stage-3 rows
    scatter2_kernel<<<dim3((Cc + 255) / 256, B), blk, 0, stream>>>(out, p2, idx1, c2m, cnt1, Cc);
    scatter3_kernel<<<dim3((Cc + 255) / 256, B), blk, 0, stream>>>(out, p3, idx1, idx2, cnt2, Cc);
}